// Round 2
// baseline (359.582 us; speedup 1.0000x reference)
//
#include <hip/hip_runtime.h>
#include <hip/hip_bf16.h>

#define B_  8
#define NQ_ 2048
#define SK_ 2048
#define D_  128
#define QT  64          // Q rows per block (16 per wave)
#define KT  64          // K/V tile
#define NT  (SK_ / KT)  // 32 k-tiles

typedef __attribute__((ext_vector_type(8))) short bf16x8;
typedef __attribute__((ext_vector_type(4))) float f32x4;

// fp32 -> bf16 round-to-nearest-even
__device__ __forceinline__ unsigned short f2bf(float f) {
    union { float f; unsigned u; } v; v.f = f;
    unsigned r = v.u + 0x7fffu + ((v.u >> 16) & 1u);
    return (unsigned short)(r >> 16);
}

__global__ __launch_bounds__(256, 1)
void sdpa_fwd(const float* __restrict__ Q, const float* __restrict__ K,
              const float* __restrict__ V, const int* __restrict__ M,
              const float* __restrict__ W, float* __restrict__ O)
{
    const int b     = blockIdx.x & 7;        // batch -> XCD-local K/V reuse
    const int qbase = (blockIdx.x >> 3) * QT;

    // +8 bf16 pad keeps ds_read_b128 rows 16B-aligned and ~conflict-free
    __shared__ unsigned short Ks[KT][D_ + 8];   // K tile, natural [k][d]
    __shared__ unsigned short Vt[D_][KT + 8];   // V tile, transposed [d][k]
    __shared__ unsigned short Ss[QT][KT + 8];   // P tile (C-layout -> A-layout)

    const int tid  = threadIdx.x;
    const int wv   = tid >> 6;
    const int lane = tid & 63;
    const int quad = lane >> 4;
    const int lq   = lane & 15;
    const int c4s  = (tid & 31) * 4;   // staging d-offset

    // ---- persistent Q A-fragments (wave rows wv*16 + lq), direct from global ----
    bf16x8 qf[4];
    {
        const float* qp = Q + ((size_t)b * NQ_ + qbase + wv * 16 + lq) * D_;
        #pragma unroll
        for (int t = 0; t < 4; ++t) {
            float4 a0 = *(const float4*)(qp + t * 32 + quad * 8);
            float4 a1 = *(const float4*)(qp + t * 32 + quad * 8 + 4);
            qf[t][0] = (short)f2bf(a0.x); qf[t][1] = (short)f2bf(a0.y);
            qf[t][2] = (short)f2bf(a0.z); qf[t][3] = (short)f2bf(a0.w);
            qf[t][4] = (short)f2bf(a1.x); qf[t][5] = (short)f2bf(a1.y);
            qf[t][6] = (short)f2bf(a1.z); qf[t][7] = (short)f2bf(a1.w);
        }
    }

    // online-softmax state in log2 domain; row = quad*4 + r of wave's 16 rows
    float m2[4], l[4];
    #pragma unroll
    for (int r = 0; r < 4; ++r) { m2[r] = -INFINITY; l[r] = 0.f; }
    f32x4 o[8];
    #pragma unroll
    for (int c = 0; c < 8; ++c) o[c] = (f32x4){0.f, 0.f, 0.f, 0.f};

    const float SCL = 0.08838834764831845f * 1.44269504088896f; // 1/sqrt(128)*log2e

    // W/mask prefetch registers (one tile ahead). Mask is int32 (bool uploaded
    // as integer per harness convention) -- 4 bytes per element.
    float    wr[4][4];
    unsigned mpack[4];
    const float* wp  = W + ((size_t)b * NQ_ + qbase + wv * 16 + quad * 4) * SK_ + lq;
    const int*   mp_ = M + ((size_t)b * NQ_ + qbase + wv * 16 + quad * 4) * SK_ + lq;
    auto load_wm = [&](int kb_el) {
        #pragma unroll
        for (int r = 0; r < 4; ++r) {
            unsigned mp = 0;
            #pragma unroll
            for (int c = 0; c < 4; ++c) {
                size_t idx = (size_t)r * SK_ + kb_el + c * 16;
                wr[r][c] = wp[idx];
                mp |= (mp_[idx] != 0 ? 1u : 0u) << c;
            }
            mpack[r] = mp;
        }
    };

    // K/V tile prefetch registers (one tile ahead)
    float4 kr[8], vr[8];
    auto load_kv = [&](int kb_el) {
        const float* kp = K + ((size_t)b * SK_ + kb_el) * D_ + c4s;
        const float* vp = V + ((size_t)b * SK_ + kb_el) * D_ + c4s;
        #pragma unroll
        for (int p = 0; p < 2; ++p) {
            int k4 = ((tid >> 5) + p * 8) * 4;
            #pragma unroll
            for (int i = 0; i < 4; ++i) {
                kr[p * 4 + i] = *(const float4*)(kp + (size_t)(k4 + i) * D_);
                vr[p * 4 + i] = *(const float4*)(vp + (size_t)(k4 + i) * D_);
            }
        }
    };

    load_kv(0);
    load_wm(0);

    #pragma unroll 1
    for (int kt = 0; kt < NT; ++kt) {
        // ---- stage prefetched K/V regs -> LDS (bf16; V transposed) ----
        #pragma unroll
        for (int p = 0; p < 2; ++p) {
            int k4 = ((tid >> 5) + p * 8) * 4;
            #pragma unroll
            for (int i = 0; i < 4; ++i) {
                float4 kv = kr[p * 4 + i];
                *(ushort4*)&Ks[k4 + i][c4s] =
                    make_ushort4(f2bf(kv.x), f2bf(kv.y), f2bf(kv.z), f2bf(kv.w));
            }
            float4 v0 = vr[p * 4 + 0], v1 = vr[p * 4 + 1];
            float4 v2 = vr[p * 4 + 2], v3 = vr[p * 4 + 3];
            // known ~16-way bank conflict on these writes (d-major stride); accepted for now
            *(ushort4*)&Vt[c4s + 0][k4] = make_ushort4(f2bf(v0.x), f2bf(v1.x), f2bf(v2.x), f2bf(v3.x));
            *(ushort4*)&Vt[c4s + 1][k4] = make_ushort4(f2bf(v0.y), f2bf(v1.y), f2bf(v2.y), f2bf(v3.y));
            *(ushort4*)&Vt[c4s + 2][k4] = make_ushort4(f2bf(v0.z), f2bf(v1.z), f2bf(v2.z), f2bf(v3.z));
            *(ushort4*)&Vt[c4s + 3][k4] = make_ushort4(f2bf(v0.w), f2bf(v1.w), f2bf(v2.w), f2bf(v3.w));
        }
        if (kt + 1 < NT) load_kv((kt + 1) * KT);   // hide K/V latency behind compute
        __syncthreads();

        // ---- S = Q Kt^T  (wave's 16 rows x 64 cols) ----
        f32x4 s[4];
        #pragma unroll
        for (int c = 0; c < 4; ++c) s[c] = (f32x4){0.f, 0.f, 0.f, 0.f};
        #pragma unroll
        for (int t = 0; t < 4; ++t) {
            #pragma unroll
            for (int c = 0; c < 4; ++c) {
                bf16x8 kf = *(const bf16x8*)&Ks[c * 16 + lq][t * 32 + quad * 8];
                s[c] = __builtin_amdgcn_mfma_f32_16x16x32_bf16(qf[t], kf, s[c], 0, 0, 0);
            }
        }

        // ---- logits (log2 domain): s * scale * w, mask -> -inf ----
        float lg[4][4];
        #pragma unroll
        for (int r = 0; r < 4; ++r)
            #pragma unroll
            for (int c = 0; c < 4; ++c) {
                float val = s[c][r] * (SCL * wr[r][c]);
                lg[r][c] = ((mpack[r] >> c) & 1u) ? -INFINITY : val;
            }
        if (kt + 1 < NT) load_wm((kt + 1) * KT);   // prefetch next tile's W/mask

        // ---- online softmax ----
        float alpha[4], p[4][4];
        #pragma unroll
        for (int r = 0; r < 4; ++r) {
            float tm = fmaxf(fmaxf(lg[r][0], lg[r][1]), fmaxf(lg[r][2], lg[r][3]));
            tm = fmaxf(tm, __shfl_xor(tm, 1));
            tm = fmaxf(tm, __shfl_xor(tm, 2));
            tm = fmaxf(tm, __shfl_xor(tm, 4));
            tm = fmaxf(tm, __shfl_xor(tm, 8));
            float mn = fmaxf(m2[r], tm);
            float ms = (mn == -INFINITY) ? 0.f : mn;   // all-masked guard
            float a  = exp2f(m2[r] - ms);
            alpha[r] = a;
            float rs = 0.f;
            #pragma unroll
            for (int c = 0; c < 4; ++c) {
                float pv = exp2f(lg[r][c] - ms);
                p[r][c] = pv;
                rs += pv;
            }
            rs += __shfl_xor(rs, 1);
            rs += __shfl_xor(rs, 2);
            rs += __shfl_xor(rs, 4);
            rs += __shfl_xor(rs, 8);
            l[r]  = l[r] * a + rs;
            m2[r] = mn;
        }
        #pragma unroll
        for (int c = 0; c < 8; ++c)
            #pragma unroll
            for (int r = 0; r < 4; ++r)
                o[c][r] *= alpha[r];

        // ---- P: C-layout -> LDS -> A-layout (own wave's rows only; same-wave
        // LDS RAW is in-order, no barrier needed) ----
        #pragma unroll
        for (int r = 0; r < 4; ++r)
            #pragma unroll
            for (int c = 0; c < 4; ++c)
                Ss[wv * 16 + quad * 4 + r][c * 16 + lq] = f2bf(p[r][c]);

        // ---- O += P Vt ----
        #pragma unroll
        for (int t = 0; t < 2; ++t) {
            bf16x8 af = *(const bf16x8*)&Ss[wv * 16 + lq][t * 32 + quad * 8];
            #pragma unroll
            for (int c = 0; c < 8; ++c) {
                bf16x8 vf = *(const bf16x8*)&Vt[c * 16 + lq][t * 32 + quad * 8];
                o[c] = __builtin_amdgcn_mfma_f32_16x16x32_bf16(af, vf, o[c], 0, 0, 0);
            }
        }
        __syncthreads();   // protect Ks/Vt before next stage
    }

    // ---- epilogue: O / l ----
    #pragma unroll
    for (int r = 0; r < 4; ++r) {
        float li = 1.0f / l[r];
        float* op = O + ((size_t)b * NQ_ + qbase + wv * 16 + quad * 4 + r) * D_;
        #pragma unroll
        for (int c = 0; c < 8; ++c)
            op[c * 16 + lq] = o[c][r] * li;
    }
}

extern "C" void kernel_launch(void* const* d_in, const int* in_sizes, int n_in,
                              void* d_out, int out_size, void* d_ws, size_t ws_size,
                              hipStream_t stream) {
    const float* Q = (const float*)d_in[0];
    const float* K = (const float*)d_in[1];
    const float* V = (const float*)d_in[2];
    const int*   M = (const int*)d_in[3];    // bool mask uploaded as int32
    const float* W = (const float*)d_in[4];
    float*       O = (float*)d_out;
    dim3 grid(B_ * (NQ_ / QT));   // 256 blocks
    sdpa_fwd<<<grid, 256, 0, stream>>>(Q, K, V, M, W, O);
}